// Round 1
// baseline (498.016 us; speedup 1.0000x reference)
//
#include <hip/hip_runtime.h>

// Sliding-window (box filter) average over seq dim, W=8, window=17, zero-padded.
// x, out: [B=8, S=8192, D=1024] fp32. Memory-bound; running-sum per column.

typedef float f32x4 __attribute__((ext_vector_type(4)));

static constexpr int W_   = 8;
static constexpr int WIN_ = 2 * W_ + 1;   // 17
static constexpr int B_   = 8;
static constexpr int S_   = 8192;
static constexpr int D_   = 1024;
static constexpr int D4_  = D_ / 4;       // 256 float4 columns
static constexpr int L_   = 128;          // timesteps per chunk
static constexpr int NC_  = S_ / L_;      // 64 chunks

template <bool GUARD>
__device__ __forceinline__ void run_chunk(const f32x4* __restrict__ px,
                                          f32x4* __restrict__ po,
                                          int t0) {
    f32x4 sum = {0.f, 0.f, 0.f, 0.f};

    // Prime: rows [t0-W, t0+W). Guarded only for edge chunks (wave-uniform).
    #pragma unroll
    for (int i = -W_; i < W_; ++i) {
        const int r = t0 + i;
        if (!GUARD || (r >= 0 && r < S_)) {
            sum += px[(size_t)r * D4_];
        }
    }

    const float inv = 1.0f / (float)WIN_;

    #pragma unroll 8
    for (int k = 0; k < L_; ++k) {
        const int t = t0 + k;
        // lead edge (cache-resident load: will be re-read as trail 17 steps later)
        if (!GUARD || (t + W_ < S_)) {
            sum += px[(size_t)(t + W_) * D4_];
        }
        f32x4 o = sum * inv;
        // output is never re-read: bypass-cache store keeps L2 for trail reads
        __builtin_nontemporal_store(o, &po[(size_t)t * D4_]);
        // trail edge (L2 hit: same wave read this row 17 iterations ago)
        if (!GUARD || (t - W_ >= 0)) {
            sum -= px[(size_t)(t - W_) * D4_];
        }
    }
}

__global__ __launch_bounds__(256)
void AverageLayer1_kernel(const float* __restrict__ x, float* __restrict__ out) {
    const int d4    = threadIdx.x;        // 0..255 -> which float4 column
    const int chunk = blockIdx.x;         // 0..NC_-1
    const int b     = blockIdx.y;         // 0..B_-1

    const size_t base = ((size_t)b * S_) * D4_ + d4;
    const f32x4* px = reinterpret_cast<const f32x4*>(x) + base;
    f32x4*       po = reinterpret_cast<f32x4*>(out) + base;
    const int t0 = chunk * L_;

    if (chunk == 0 || chunk == NC_ - 1) {
        run_chunk<true>(px, po, t0);
    } else {
        run_chunk<false>(px, po, t0);
    }
}

extern "C" void kernel_launch(void* const* d_in, const int* in_sizes, int n_in,
                              void* d_out, int out_size, void* d_ws, size_t ws_size,
                              hipStream_t stream) {
    const float* x = (const float*)d_in[0];
    float* out = (float*)d_out;

    dim3 grid(NC_, B_);   // 64 x 8 = 512 blocks
    dim3 block(256);
    AverageLayer1_kernel<<<grid, block, 0, stream>>>(x, out);
}